// Round 11
// baseline (63.166 us; speedup 1.0000x reference)
//
#include <hip/hip_runtime.h>
#include <hip/hip_bf16.h>

typedef unsigned short u16;
typedef unsigned int u32;
typedef __attribute__((ext_vector_type(8))) short bf16x8;
typedef __attribute__((ext_vector_type(4))) float f32x4;

#define S_LEN 2048
#define NHQ   16
#define NHKV  4
#define HD    64
#define KVBLK 64
#define LPAD  72          // 144B row stride
#define KVSTR (NHKV*HD)   // 256
#define QSTR  (NHQ*HD)    // 1024
// (1/sqrt(64)) * log2(e): scores land in exp2 domain
#define QSCALE 0.18033688011112042f
#define DEFER_THR 8.0f

__device__ __forceinline__ u32 cvt2(float lo, float hi) {
    __hip_bfloat162 hh = __float22bfloat162_rn(make_float2(lo, hi));
    union { __hip_bfloat162 h; u32 u; } c; c.h = hh; return c.u;   // v_cvt_pk_bf16_f32
}
__device__ __forceinline__ u16 cvt1(float x) {
    __hip_bfloat16 hh = __float2bfloat16(x);
    union { __hip_bfloat16 h; u16 u; } c; c.h = hh; return c.u;
}

__global__ __launch_bounds__(256, 3)
void gqa_fwd_kernel(const float* __restrict__ Qp, const float* __restrict__ Kp,
                    const float* __restrict__ Vp, float* __restrict__ Op)
{
    __shared__ __align__(16) u16 Kl[2][KVBLK][LPAD];  // K dbuf [kv][d]
    __shared__ __align__(16) u16 Vt[2][HD][LPAD];     // V dbuf transposed [dv][kv]
    __shared__ __align__(16) u16 Pl[4][16][LPAD];     // per-wave P [q][kv]

    const int tid  = threadIdx.x;
    const int w    = tid >> 6;         // 0..3
    const int lane = tid & 63;
    const int l16  = lane & 15;
    const int quad = lane >> 4;

    // 1024 blocks = 32 heads x 32 q-tiles of 64 rows; 3 blocks/CU resident.
    // qt mapping: residency groups {bid>>5 = i, i+8, i+16, i+24} carry qt
    // {31-i, 16+i, 15-i, i} -> per-CU slot sum = 66 uniform under the
    // stride-256 co-residency model; globally descending for LPT backfill.
    const int bid  = blockIdx.x;
    const int head = bid & 31;        // bid&7 spans (kvh,b): XCD L2 stream locality
    const int g    = bid >> 5;
    const int gi   = g & 7;
    const int gs   = g >> 3;
    const int qt   = (gs == 0) ? (31 - gi) : (gs == 1) ? (16 + gi)
                   : (gs == 2) ? (15 - gi) : gi;
    const int kvh  = head & 3;
    const int b    = (head >> 2) & 1;
    const int qh   = kvh * 4 + (head >> 3);

    const int relq = w * 16 + l16;           // q row within the 64-row tile
    const int qrow = qt * 64 + relq;

    const float* Kbase = Kp + (size_t)b * S_LEN * KVSTR + kvh*HD;
    const float* Vbase = Vp + (size_t)b * S_LEN * KVSTR + kvh*HD;
    const float* qp    = Qp + ((size_t)b * S_LEN + qrow) * QSTR + qh*HD;
    float*       ob    = Op + ((size_t)(b*NHQ + qh) * S_LEN + qrow) * HD;

    // staging maps (256 threads stage one 64x64 K + V tile, 16 elems each):
    // K row-major b128 stores; V transposed contiguous scalar b16 stores.
    const int krow = tid >> 2;           // 0..63
    const int kd   = (tid & 3) * 16;     // 0,16,32,48
    const int vrow = tid & 63;           // kv
    const int vd0  = w * 16;             // 0,16,32,48

    float4 kpf[4], vpf[4];   // in-flight staging registers

    auto ISSUE = [&](int tt) {
        const float* kp = Kbase + (size_t)(tt*KVBLK + krow)*KVSTR + kd;
        const float* vp = Vbase + (size_t)(tt*KVBLK + vrow)*KVSTR + vd0;
        #pragma unroll
        for (int ii = 0; ii < 4; ++ii) {
            kpf[ii] = *(const float4*)(kp + 4*ii);
            vpf[ii] = *(const float4*)(vp + 4*ii);
        }
        asm volatile("" ::: "memory");   // pin issue point
    };
    auto WRITE = [&](int bf) {
        *(uint4*)(&Kl[bf][krow][kd]) = make_uint4(
            cvt2(kpf[0].x,kpf[0].y), cvt2(kpf[0].z,kpf[0].w),
            cvt2(kpf[1].x,kpf[1].y), cvt2(kpf[1].z,kpf[1].w));
        *(uint4*)(&Kl[bf][krow][kd+8]) = make_uint4(
            cvt2(kpf[2].x,kpf[2].y), cvt2(kpf[2].z,kpf[2].w),
            cvt2(kpf[3].x,kpf[3].y), cvt2(kpf[3].z,kpf[3].w));
        #pragma unroll
        for (int ii = 0; ii < 4; ++ii) {
            Vt[bf][vd0+4*ii+0][vrow] = cvt1(vpf[ii].x);
            Vt[bf][vd0+4*ii+1][vrow] = cvt1(vpf[ii].y);
            Vt[bf][vd0+4*ii+2][vrow] = cvt1(vpf[ii].z);
            Vt[bf][vd0+4*ii+3][vrow] = cvt1(vpf[ii].w);
        }
    };

    // ---- Q fragments (B operand of swapped QK^T), scale*log2e folded ----
    bf16x8 qf[2];
    #pragma unroll
    for (int kk = 0; kk < 2; ++kk) {
        const float4 x = *(const float4*)(qp + kk*32 + quad*8);
        const float4 y = *(const float4*)(qp + kk*32 + quad*8 + 4);
        union { u32 u[4]; bf16x8 v; } t4;
        t4.u[0] = cvt2(x.x*QSCALE, x.y*QSCALE);
        t4.u[1] = cvt2(x.z*QSCALE, x.w*QSCALE);
        t4.u[2] = cvt2(y.x*QSCALE, y.y*QSCALE);
        t4.u[3] = cvt2(y.z*QSCALE, y.w*QSCALE);
        qf[kk] = t4.v;
    }

    f32x4 oacc[4];   // O^T: oacc[nb][r] = O[q=l16][dv = nb*16 + quad*4 + r]
    #pragma unroll
    for (int nb = 0; nb < 4; ++nb) { oacc[nb][0]=0.f; oacc[nb][1]=0.f; oacc[nb][2]=0.f; oacc[nb][3]=0.f; }
    float m_s = -1e30f;   // running max for q = l16 (wave-uniform across quads)
    float l_p = 0.f;      // per-quad partial row-sum; reduced in epilogue

    // ---- prologue: stage tile 0 into buf 0 ----
    ISSUE(0);
    WRITE(0);
    __syncthreads();

    for (int t = 0; t <= qt; ++t) {
        const bool pf_on = (t < qt);
        if (pf_on) ISSUE(t + 1);   // latency hides under this slot's compute

        const int bf = t & 1;
        // ---- swapped QK^T: lane holds S[kv = nb*16+quad*4+r][q = l16] ----
        f32x4 s[4];
        __builtin_amdgcn_s_setprio(1);
        #pragma unroll
        for (int nb = 0; nb < 4; ++nb) {
            f32x4 acc = {0.f,0.f,0.f,0.f};
            #pragma unroll
            for (int kk = 0; kk < 2; ++kk) {
                bf16x8 kf = *(const bf16x8*)(&Kl[bf][nb*16 + l16][kk*32 + quad*8]);
                acc = __builtin_amdgcn_mfma_f32_16x16x32_bf16(kf, qf[kk], acc, 0, 0, 0);
            }
            s[nb] = acc;
        }
        __builtin_amdgcn_s_setprio(0);

        // ---- causal mask on the diagonal (last) tile ----
        if (t == qt) {
            #pragma unroll
            for (int nb = 0; nb < 4; ++nb)
                #pragma unroll
                for (int r = 0; r < 4; ++r)
                    if (nb*16 + quad*4 + r > relq) s[nb][r] = -1e30f;
        }

        // ---- local 16-max (tree) ----
        float a0 = fmaxf(fmaxf(s[0][0], s[0][1]), fmaxf(s[0][2], s[0][3]));
        float a1 = fmaxf(fmaxf(s[1][0], s[1][1]), fmaxf(s[1][2], s[1][3]));
        float a2 = fmaxf(fmaxf(s[2][0], s[2][1]), fmaxf(s[2][2], s[2][3]));
        float a3 = fmaxf(fmaxf(s[3][0], s[3][1]), fmaxf(s[3][2], s[3][3]));
        const float lmax = fmaxf(fmaxf(a0, a1), fmaxf(a2, a3));

        // ---- T13 defer-max: reduce+rescale only when the max grew ----
        if (!__all(lmax <= m_s + DEFER_THR)) {
            float rmax = fmaxf(lmax, __shfl_xor(lmax, 16));
            rmax = fmaxf(rmax, __shfl_xor(rmax, 32));
            const float mnew = fmaxf(m_s, rmax);
            const float cf   = __builtin_amdgcn_exp2f(m_s - mnew);
            m_s = mnew;
            l_p *= cf;
            #pragma unroll
            for (int nb = 0; nb < 4; ++nb)
                #pragma unroll
                for (int r = 0; r < 4; ++r) oacc[nb][r] *= cf;
        }

        // ---- exp2 + partial row-sum (pairwise trees) ----
        float ps[4];
        #pragma unroll
        for (int nb = 0; nb < 4; ++nb) {
            const float p0 = __builtin_amdgcn_exp2f(s[nb][0] - m_s);
            const float p1 = __builtin_amdgcn_exp2f(s[nb][1] - m_s);
            const float p2 = __builtin_amdgcn_exp2f(s[nb][2] - m_s);
            const float p3 = __builtin_amdgcn_exp2f(s[nb][3] - m_s);
            s[nb][0]=p0; s[nb][1]=p1; s[nb][2]=p2; s[nb][3]=p3;
            ps[nb] = (p0 + p1) + (p2 + p3);
        }
        l_p += (ps[0] + ps[1]) + (ps[2] + ps[3]);

        // ---- P -> Pl (uint2 pk stores), read back as B-fragment ----
        #pragma unroll
        for (int nb = 0; nb < 4; ++nb)
            *(uint2*)(&Pl[w][l16][nb*16 + quad*4]) =
                make_uint2(cvt2(s[nb][0], s[nb][1]), cvt2(s[nb][2], s[nb][3]));
        bf16x8 pfrag[2];
        #pragma unroll
        for (int kk = 0; kk < 2; ++kk)
            pfrag[kk] = *(const bf16x8*)(&Pl[w][l16][kk*32 + quad*8]);

        // ---- O^T += V^T P^T : A = Vt rows (dv), B = P cols (q=l16) ----
        __builtin_amdgcn_s_setprio(1);
        #pragma unroll
        for (int nb = 0; nb < 4; ++nb) {
            #pragma unroll
            for (int kk = 0; kk < 2; ++kk) {
                bf16x8 vf = *(const bf16x8*)(&Vt[bf][nb*16 + l16][kk*32 + quad*8]);
                oacc[nb] = __builtin_amdgcn_mfma_f32_16x16x32_bf16(vf, pfrag[kk], oacc[nb], 0, 0, 0);
            }
        }
        __builtin_amdgcn_s_setprio(0);

        // ---- write prefetched tile to the other buffer; one barrier/slot ----
        if (pf_on) WRITE(bf ^ 1);
        __syncthreads();
    }

    // ---- epilogue: reduce l across quads; O^T store, float4, lane-local ----
    l_p += __shfl_xor(l_p, 16);
    l_p += __shfl_xor(l_p, 32);
    const float inv = 1.0f / l_p;
    #pragma unroll
    for (int nb = 0; nb < 4; ++nb) {
        float4 o4;
        o4.x = oacc[nb][0] * inv;
        o4.y = oacc[nb][1] * inv;
        o4.z = oacc[nb][2] * inv;
        o4.w = oacc[nb][3] * inv;
        *(float4*)(ob + nb*16 + quad*4) = o4;
    }
}

extern "C" void kernel_launch(void* const* d_in, const int* in_sizes, int n_in,
                              void* d_out, int out_size, void* d_ws, size_t ws_size,
                              hipStream_t stream) {
    const float* Q = (const float*)d_in[0];
    const float* K = (const float*)d_in[1];
    const float* V = (const float*)d_in[2];
    // d_in[3] (tril mask) computed analytically, never read.
    float* O = (float*)d_out;
    gqa_fwd_kernel<<<dim3(1024), dim3(256), 0, stream>>>(Q, K, V, O);
}

// Round 12
// 48.352 us; speedup vs baseline: 1.3064x; 1.3064x over previous
//
#include <hip/hip_runtime.h>
#include <hip/hip_bf16.h>

typedef unsigned short u16;
typedef unsigned int u32;
typedef __attribute__((ext_vector_type(8))) short bf16x8;
typedef __attribute__((ext_vector_type(4))) float f32x4;

#define S_LEN 2048
#define NHQ   16
#define NHKV  4
#define HD    64
#define KVBLK 64
#define PPAD  72             // Pl row stride (u16)
#define KVSTR (NHKV*HD)      // 256
#define QSTR  (NHQ*HD)       // 1024
#define TILE_U16 4096        // one 64x64 bf16 tile
#define HEAD_U16 (32*TILE_U16)
#define VT_OFF   (8*HEAD_U16)   // u16 offset of V region in ws (2 MB)
// (1/sqrt(64)) * log2(e)
#define QSCALE 0.18033688011112042f
#define DEFER_THR 8.0f

__device__ __forceinline__ u32 cvt2(float lo, float hi) {
    __hip_bfloat162 hh = __float22bfloat162_rn(make_float2(lo, hi));
    union { __hip_bfloat162 h; u32 u; } c; c.h = hh; return c.u;   // v_cvt_pk_bf16_f32
}
__device__ __forceinline__ u16 cvt1(float x) {
    __hip_bfloat16 hh = __float2bfloat16(x);
    union { __hip_bfloat16 h; u16 u; } c; c.h = hh; return c.u;
}

typedef __attribute__((address_space(3))) u32 lds_u32;
typedef __attribute__((address_space(1))) const u32 glb_u32;
__device__ __forceinline__ void gld_lds16(const void* g, void* l) {
    // per-lane global src; wave-uniform LDS dest + lane*16 (HW semantics)
    __builtin_amdgcn_global_load_lds((glb_u32*)g, (lds_u32*)l, 16, 0, 0);
}

// ---------- pre-pass: K,V -> bf16, tiled, V transposed, XOR-swizzled ----------
// layout: ws[(b*4+kvh)*32 + t][row][col ^ ((row&7)<<3)]  (u16; row=kv for K, row=dv for V)
__global__ __launch_bounds__(256)
void prep_kv(const float* __restrict__ Kp, const float* __restrict__ Vp,
             u16* __restrict__ WS)
{
    const int bid = blockIdx.x;          // = (b*4+kvh)*32 + t
    const int t   = bid & 31;
    const int kvh = (bid >> 5) & 3;
    const int b   = bid >> 7;
    const int tid = threadIdx.x;

    u16* kt = WS + (size_t)bid * TILE_U16;
    u16* vt = WS + VT_OFF + (size_t)bid * TILE_U16;

    {   // K: row r, 16 cols starting at c16
        const int r   = tid >> 2;
        const int c16 = (tid & 3) << 4;
        const float* kg = Kp + ((size_t)(b*S_LEN) + t*64 + r) * KVSTR + kvh*HD + c16;
        const float4 a  = *(const float4*)(kg);
        const float4 b4 = *(const float4*)(kg + 4);
        const float4 c  = *(const float4*)(kg + 8);
        const float4 d  = *(const float4*)(kg + 12);
        const int swz = (r & 7) << 3;
        *(uint4*)(kt + r*64 + (c16 ^ swz)) =
            make_uint4(cvt2(a.x,a.y), cvt2(a.z,a.w), cvt2(b4.x,b4.y), cvt2(b4.z,b4.w));
        *(uint4*)(kt + r*64 + ((c16+8) ^ swz)) =
            make_uint4(cvt2(c.x,c.y), cvt2(c.z,c.w), cvt2(d.x,d.y), cvt2(d.z,d.w));
    }
    {   // V transpose: lane kv, dv rows dv0..dv0+15
        const int kv  = tid & 63;
        const int dv0 = (tid >> 6) << 4;
        const float* vg = Vp + ((size_t)(b*S_LEN) + t*64 + kv) * KVSTR + kvh*HD + dv0;
        float4 vv[4];
        vv[0] = *(const float4*)(vg);
        vv[1] = *(const float4*)(vg + 4);
        vv[2] = *(const float4*)(vg + 8);
        vv[3] = *(const float4*)(vg + 12);
        #pragma unroll
        for (int g4 = 0; g4 < 4; ++g4) {
            const int dv = dv0 + g4*4;
            vt[(dv+0)*64 + (kv ^ (((dv+0)&7)<<3))] = cvt1(vv[g4].x);
            vt[(dv+1)*64 + (kv ^ (((dv+1)&7)<<3))] = cvt1(vv[g4].y);
            vt[(dv+2)*64 + (kv ^ (((dv+2)&7)<<3))] = cvt1(vv[g4].z);
            vt[(dv+3)*64 + (kv ^ (((dv+3)&7)<<3))] = cvt1(vv[g4].w);
        }
    }
}

// ---------- main attention ----------
__global__ __launch_bounds__(256, 2)
void gqa_fwd_kernel(const float* __restrict__ Qp, const u16* __restrict__ WS,
                    float* __restrict__ Op)
{
    __shared__ __align__(16) u16 Kl[2][TILE_U16];   // linear (DMA dest), swizzled content
    __shared__ __align__(16) u16 Vl[2][TILE_U16];
    __shared__ __align__(16) u16 Pl[4][16][PPAD];

    const int tid  = threadIdx.x;
    const int w    = tid >> 6;
    const int lane = tid & 63;
    const int l16  = lane & 15;
    const int quad = lane >> 4;

    // 512 uniform blocks: 32 heads x 16 pairs {31-j, j} of 64-row q-tiles (34 slots each).
    const int bid  = blockIdx.x;
    const int head = bid & 31;      // bid&7 spans (kvh,b): XCD L2 stream locality
    const int j    = bid >> 5;      // 0..15
    const int kvh  = head & 3;
    const int b    = (head >> 2) & 1;
    const int qh   = kvh * 4 + (head >> 3);

    const u16* Kt = WS + (size_t)(b*4 + kvh) * HEAD_U16;
    const u16* Vt = WS + VT_OFF + (size_t)(b*4 + kvh) * HEAD_U16;
    const float* Qhead = Qp + (size_t)b * S_LEN * QSTR + qh*HD;
    float*       Ohead = Op + (size_t)(b*NHQ + qh) * S_LEN * HD;

    // DMA: wave w copies byte range [w*2048, w*2048+2048) of each 8KB tile
    const size_t gofs = (size_t)w*2048 + (size_t)lane*16;

    // swizzled ds_read addressing (content pre-swizzled at source: rule #21)
    const int rswz = (l16 & 7) << 3;    // u16 XOR within a 64-u16 row
    const int relq = w*16 + l16;

    #pragma unroll 1
    for (int pass = 0; pass < 2; ++pass) {
        const int qt   = pass ? j : (31 - j);
        const int qrow = qt*64 + relq;

        // prologue DMA of tile 0 overlaps Q-fragment load
        {
            const char* kg = (const char*)Kt + gofs;          // tile 0
            const char* vg = (const char*)Vt + gofs;
            char* kl = (char*)(&Kl[0][0]) + w*2048;
            char* vl = (char*)(&Vl[0][0]) + w*2048;
            gld_lds16(kg, kl);  gld_lds16(kg + 1024, kl + 1024);
            gld_lds16(vg, vl);  gld_lds16(vg + 1024, vl + 1024);
        }

        // ---- Q fragment (B operand of swapped QK^T), scale*log2e folded ----
        bf16x8 qf[2];
        {
            const float* qp = Qhead + (size_t)qrow * QSTR;
            #pragma unroll
            for (int kk = 0; kk < 2; ++kk) {
                const float4 x = *(const float4*)(qp + kk*32 + quad*8);
                const float4 y = *(const float4*)(qp + kk*32 + quad*8 + 4);
                union { u32 u[4]; bf16x8 v; } t4;
                t4.u[0] = cvt2(x.x*QSCALE, x.y*QSCALE);
                t4.u[1] = cvt2(x.z*QSCALE, x.w*QSCALE);
                t4.u[2] = cvt2(y.x*QSCALE, y.y*QSCALE);
                t4.u[3] = cvt2(y.z*QSCALE, y.w*QSCALE);
                qf[kk] = t4.v;
            }
        }

        f32x4 oacc[4];   // O^T: oacc[nb][r] = O[q=l16][dv = nb*16 + quad*4 + r]
        #pragma unroll
        for (int nb = 0; nb < 4; ++nb) { oacc[nb][0]=0.f; oacc[nb][1]=0.f; oacc[nb][2]=0.f; oacc[nb][3]=0.f; }
        float m_s = -1e30f;
        float l_p = 0.f;      // per-quad partial; reduced in epilogue

        __syncthreads();      // tile-0 DMA drained (vmcnt 0) + all waves ready

        for (int t = 0; t <= qt; ++t) {
            const int bf = t & 1;
            if (t < qt) {   // DMA next tile into other buffer; overlaps compute
                const char* kg = (const char*)(Kt + (size_t)(t+1)*TILE_U16) + gofs;
                const char* vg = (const char*)(Vt + (size_t)(t+1)*TILE_U16) + gofs;
                char* kl = (char*)(&Kl[bf^1][0]) + w*2048;
                char* vl = (char*)(&Vl[bf^1][0]) + w*2048;
                gld_lds16(kg, kl);  gld_lds16(kg + 1024, kl + 1024);
                gld_lds16(vg, vl);  gld_lds16(vg + 1024, vl + 1024);
            }

            // ---- swapped QK^T: lane holds S[kv = nb*16+quad*4+r][q = l16] ----
            f32x4 s[4];
            __builtin_amdgcn_s_setprio(1);
            #pragma unroll
            for (int nb = 0; nb < 4; ++nb) {
                f32x4 acc = {0.f,0.f,0.f,0.f};
                #pragma unroll
                for (int kk = 0; kk < 2; ++kk) {
                    bf16x8 kf = *(const bf16x8*)(&Kl[bf][(nb*16 + l16)*64 + ((kk*32 + quad*8) ^ rswz)]);
                    acc = __builtin_amdgcn_mfma_f32_16x16x32_bf16(kf, qf[kk], acc, 0, 0, 0);
                }
                s[nb] = acc;
            }
            __builtin_amdgcn_s_setprio(0);

            // ---- causal mask on the diagonal (last) tile ----
            if (t == qt) {
                #pragma unroll
                for (int nb = 0; nb < 4; ++nb)
                    #pragma unroll
                    for (int r = 0; r < 4; ++r)
                        if (nb*16 + quad*4 + r > relq) s[nb][r] = -1e30f;
            }

            // ---- local 16-max (tree) ----
            float a0 = fmaxf(fmaxf(s[0][0], s[0][1]), fmaxf(s[0][2], s[0][3]));
            float a1 = fmaxf(fmaxf(s[1][0], s[1][1]), fmaxf(s[1][2], s[1][3]));
            float a2 = fmaxf(fmaxf(s[2][0], s[2][1]), fmaxf(s[2][2], s[2][3]));
            float a3 = fmaxf(fmaxf(s[3][0], s[3][1]), fmaxf(s[3][2], s[3][3]));
            const float lmax = fmaxf(fmaxf(a0, a1), fmaxf(a2, a3));

            // ---- T13 defer-max: reduce+rescale only when the max grew ----
            if (!__all(lmax <= m_s + DEFER_THR)) {
                float rmax = fmaxf(lmax, __shfl_xor(lmax, 16));
                rmax = fmaxf(rmax, __shfl_xor(rmax, 32));
                const float mnew = fmaxf(m_s, rmax);
                const float cf   = __builtin_amdgcn_exp2f(m_s - mnew);
                m_s = mnew;
                l_p *= cf;
                #pragma unroll
                for (int nb = 0; nb < 4; ++nb)
                    #pragma unroll
                    for (int r = 0; r < 4; ++r) oacc[nb][r] *= cf;
            }

            // ---- exp2 + partial row-sum ----
            float ps[4];
            #pragma unroll
            for (int nb = 0; nb < 4; ++nb) {
                const float p0 = __builtin_amdgcn_exp2f(s[nb][0] - m_s);
                const float p1 = __builtin_amdgcn_exp2f(s[nb][1] - m_s);
                const float p2 = __builtin_amdgcn_exp2f(s[nb][2] - m_s);
                const float p3 = __builtin_amdgcn_exp2f(s[nb][3] - m_s);
                s[nb][0]=p0; s[nb][1]=p1; s[nb][2]=p2; s[nb][3]=p3;
                ps[nb] = (p0 + p1) + (p2 + p3);
            }
            l_p += (ps[0] + ps[1]) + (ps[2] + ps[3]);

            // ---- P -> Pl (uint2 pk stores), read back as B-fragment ----
            #pragma unroll
            for (int nb = 0; nb < 4; ++nb)
                *(uint2*)(&Pl[w][l16][nb*16 + quad*4]) =
                    make_uint2(cvt2(s[nb][0], s[nb][1]), cvt2(s[nb][2], s[nb][3]));
            bf16x8 pfrag[2];
            #pragma unroll
            for (int kk = 0; kk < 2; ++kk)
                pfrag[kk] = *(const bf16x8*)(&Pl[w][l16][kk*32 + quad*8]);

            // ---- O^T += V^T P^T (A = Vt rows, B = P cols) ----
            __builtin_amdgcn_s_setprio(1);
            #pragma unroll
            for (int nb = 0; nb < 4; ++nb) {
                #pragma unroll
                for (int kk = 0; kk < 2; ++kk) {
                    bf16x8 vf = *(const bf16x8*)(&Vl[bf][(nb*16 + l16)*64 + ((kk*32 + quad*8) ^ rswz)]);
                    oacc[nb] = __builtin_amdgcn_mfma_f32_16x16x32_bf16(vf, pfrag[kk], oacc[nb], 0, 0, 0);
                }
            }
            __builtin_amdgcn_s_setprio(0);

            __syncthreads();   // drains next-tile DMA (vmcnt 0) + role sync
        }

        // ---- epilogue: reduce l across quads; O^T store, float4, lane-local ----
        l_p += __shfl_xor(l_p, 16);
        l_p += __shfl_xor(l_p, 32);
        const float inv = 1.0f / l_p;
        float* ob = Ohead + (size_t)qrow * HD;
        #pragma unroll
        for (int nb = 0; nb < 4; ++nb) {
            float4 o4;
            o4.x = oacc[nb][0] * inv;
            o4.y = oacc[nb][1] * inv;
            o4.z = oacc[nb][2] * inv;
            o4.w = oacc[nb][3] * inv;
            *(float4*)(ob + nb*16 + quad*4) = o4;
        }
    }
}

extern "C" void kernel_launch(void* const* d_in, const int* in_sizes, int n_in,
                              void* d_out, int out_size, void* d_ws, size_t ws_size,
                              hipStream_t stream) {
    const float* Q = (const float*)d_in[0];
    const float* K = (const float*)d_in[1];
    const float* V = (const float*)d_in[2];
    // d_in[3] (tril mask) computed analytically, never read.
    float* O  = (float*)d_out;
    u16*  WS = (u16*)d_ws;   // 4 MB: [2MB K tiles][2MB V tiles], bf16 swizzled

    prep_kv<<<dim3(256), dim3(256), 0, stream>>>(K, V, WS);
    gqa_fwd_kernel<<<dim3(512), dim3(256), 0, stream>>>(Q, WS, O);
}

// Round 13
// 46.188 us; speedup vs baseline: 1.3676x; 1.0469x over previous
//
#include <hip/hip_runtime.h>
#include <hip/hip_bf16.h>

typedef unsigned short u16;
typedef unsigned int u32;
typedef __attribute__((ext_vector_type(8))) short bf16x8;
typedef __attribute__((ext_vector_type(4))) float f32x4;

#define S_LEN 2048
#define NHQ   16
#define NHKV  4
#define HD    64
#define KVBLK 64
#define PPAD  72             // Pl row stride (u16)
#define KVSTR (NHKV*HD)      // 256
#define QSTR  (NHQ*HD)       // 1024
#define TILE_U16 4096        // one 64x64 bf16 tile
#define HEAD_U16 (32*TILE_U16)
#define VT_OFF   (8*HEAD_U16)   // u16 offset of V region in ws (2 MB)
// (1/sqrt(64)) * log2(e)
#define QSCALE 0.18033688011112042f
#define DEFER_THR 8.0f

__device__ __forceinline__ u32 cvt2(float lo, float hi) {
    __hip_bfloat162 hh = __float22bfloat162_rn(make_float2(lo, hi));
    union { __hip_bfloat162 h; u32 u; } c; c.h = hh; return c.u;   // v_cvt_pk_bf16_f32
}
__device__ __forceinline__ u16 cvt1(float x) {
    __hip_bfloat16 hh = __float2bfloat16(x);
    union { __hip_bfloat16 h; u16 u; } c; c.h = hh; return c.u;
}

typedef __attribute__((address_space(3))) u32 lds_u32;
typedef __attribute__((address_space(1))) const u32 glb_u32;
__device__ __forceinline__ void gld_lds16(const void* g, void* l) {
    // per-lane global src; wave-uniform LDS dest + lane*16 (HW semantics)
    __builtin_amdgcn_global_load_lds((glb_u32*)g, (lds_u32*)l, 16, 0, 0);
}

// ---------- pre-pass: K,V -> bf16, tiled, V transposed, XOR-swizzled ----------
// layout: ws[(b*4+kvh)*32 + t][row][col ^ ((row&7)<<3)]  (u16; row=kv for K, row=dv for V)
__global__ __launch_bounds__(256)
void prep_kv(const float* __restrict__ Kp, const float* __restrict__ Vp,
             u16* __restrict__ WS)
{
    const int bid = blockIdx.x;          // = (b*4+kvh)*32 + t
    const int t   = bid & 31;
    const int kvh = (bid >> 5) & 3;
    const int b   = bid >> 7;
    const int tid = threadIdx.x;

    u16* kt = WS + (size_t)bid * TILE_U16;
    u16* vt = WS + VT_OFF + (size_t)bid * TILE_U16;

    {   // K: row r, 16 cols starting at c16
        const int r   = tid >> 2;
        const int c16 = (tid & 3) << 4;
        const float* kg = Kp + ((size_t)(b*S_LEN) + t*64 + r) * KVSTR + kvh*HD + c16;
        const float4 a  = *(const float4*)(kg);
        const float4 b4 = *(const float4*)(kg + 4);
        const float4 c  = *(const float4*)(kg + 8);
        const float4 d  = *(const float4*)(kg + 12);
        const int swz = (r & 7) << 3;
        *(uint4*)(kt + r*64 + (c16 ^ swz)) =
            make_uint4(cvt2(a.x,a.y), cvt2(a.z,a.w), cvt2(b4.x,b4.y), cvt2(b4.z,b4.w));
        *(uint4*)(kt + r*64 + ((c16+8) ^ swz)) =
            make_uint4(cvt2(c.x,c.y), cvt2(c.z,c.w), cvt2(d.x,d.y), cvt2(d.z,d.w));
    }
    {   // V transpose: lane kv, dv rows dv0..dv0+15
        const int kv  = tid & 63;
        const int dv0 = (tid >> 6) << 4;
        const float* vg = Vp + ((size_t)(b*S_LEN) + t*64 + kv) * KVSTR + kvh*HD + dv0;
        float4 vv[4];
        vv[0] = *(const float4*)(vg);
        vv[1] = *(const float4*)(vg + 4);
        vv[2] = *(const float4*)(vg + 8);
        vv[3] = *(const float4*)(vg + 12);
        #pragma unroll
        for (int g4 = 0; g4 < 4; ++g4) {
            const int dv = dv0 + g4*4;
            vt[(dv+0)*64 + (kv ^ (((dv+0)&7)<<3))] = cvt1(vv[g4].x);
            vt[(dv+1)*64 + (kv ^ (((dv+1)&7)<<3))] = cvt1(vv[g4].y);
            vt[(dv+2)*64 + (kv ^ (((dv+2)&7)<<3))] = cvt1(vv[g4].z);
            vt[(dv+3)*64 + (kv ^ (((dv+3)&7)<<3))] = cvt1(vv[g4].w);
        }
    }
}

// ---------- main attention ----------
__global__ __launch_bounds__(256, 3)
void gqa_fwd_kernel(const float* __restrict__ Qp, const u16* __restrict__ WS,
                    float* __restrict__ Op)
{
    __shared__ __align__(16) u16 Kl[2][TILE_U16];   // linear (DMA dest), swizzled content
    __shared__ __align__(16) u16 Vl[2][TILE_U16];
    __shared__ __align__(16) u16 Pl[4][16][PPAD];

    const int tid  = threadIdx.x;
    const int w    = tid >> 6;
    const int lane = tid & 63;
    const int l16  = lane & 15;
    const int quad = lane >> 4;

    // 1024 blocks = 32 heads x 32 q-tiles of 64 rows; qt descending (LPT).
    // 3 blocks/CU resident -> 3 independent barrier domains per SIMD.
    const int bid  = blockIdx.x;
    const int head = bid & 31;      // bid&7 spans (kvh,b): one K/V stream per XCD L2
    const int qt   = 31 - (bid >> 5);
    const int kvh  = head & 3;
    const int b    = (head >> 2) & 1;
    const int qh   = kvh * 4 + (head >> 3);

    const u16* Kt = WS + (size_t)(b*4 + kvh) * HEAD_U16;
    const u16* Vt = WS + VT_OFF + (size_t)(b*4 + kvh) * HEAD_U16;

    const int relq = w*16 + l16;
    const int qrow = qt*64 + relq;
    const float* qp = Qp + ((size_t)b * S_LEN + qrow) * QSTR + qh*HD;
    float*       ob = Op + ((size_t)(b*NHQ + qh) * S_LEN + qrow) * HD;

    // DMA: wave w copies byte range [w*2048, w*2048+2048) of each 8KB tile
    const size_t gofs = (size_t)w*2048 + (size_t)lane*16;

    // swizzled ds_read addressing (content pre-swizzled at source: rule #21)
    const int rswz = (l16 & 7) << 3;    // u16 XOR within a 64-u16 row

    // prologue DMA of tile 0 overlaps Q-fragment load
    {
        const char* kg = (const char*)Kt + gofs;          // tile 0
        const char* vg = (const char*)Vt + gofs;
        char* kl = (char*)(&Kl[0][0]) + w*2048;
        char* vl = (char*)(&Vl[0][0]) + w*2048;
        gld_lds16(kg, kl);  gld_lds16(kg + 1024, kl + 1024);
        gld_lds16(vg, vl);  gld_lds16(vg + 1024, vl + 1024);
    }

    // ---- Q fragment (B operand of swapped QK^T), scale*log2e folded ----
    bf16x8 qf[2];
    #pragma unroll
    for (int kk = 0; kk < 2; ++kk) {
        const float4 x = *(const float4*)(qp + kk*32 + quad*8);
        const float4 y = *(const float4*)(qp + kk*32 + quad*8 + 4);
        union { u32 u[4]; bf16x8 v; } t4;
        t4.u[0] = cvt2(x.x*QSCALE, x.y*QSCALE);
        t4.u[1] = cvt2(x.z*QSCALE, x.w*QSCALE);
        t4.u[2] = cvt2(y.x*QSCALE, y.y*QSCALE);
        t4.u[3] = cvt2(y.z*QSCALE, y.w*QSCALE);
        qf[kk] = t4.v;
    }

    f32x4 oacc[4];   // O^T: oacc[nb][r] = O[q=l16][dv = nb*16 + quad*4 + r]
    #pragma unroll
    for (int nb = 0; nb < 4; ++nb) { oacc[nb][0]=0.f; oacc[nb][1]=0.f; oacc[nb][2]=0.f; oacc[nb][3]=0.f; }
    float m_s = -1e30f;
    float l_p = 0.f;      // per-quad partial; reduced in epilogue

    __syncthreads();      // tile-0 DMA drained + all waves ready

    for (int t = 0; t <= qt; ++t) {
        const int bf = t & 1;
        if (t < qt) {   // DMA next tile into other buffer; overlaps compute
            const char* kg = (const char*)(Kt + (size_t)(t+1)*TILE_U16) + gofs;
            const char* vg = (const char*)(Vt + (size_t)(t+1)*TILE_U16) + gofs;
            char* kl = (char*)(&Kl[bf^1][0]) + w*2048;
            char* vl = (char*)(&Vl[bf^1][0]) + w*2048;
            gld_lds16(kg, kl);  gld_lds16(kg + 1024, kl + 1024);
            gld_lds16(vg, vl);  gld_lds16(vg + 1024, vl + 1024);
        }

        // ---- swapped QK^T: lane holds S[kv = nb*16+quad*4+r][q = l16] ----
        f32x4 s[4];
        __builtin_amdgcn_s_setprio(1);
        #pragma unroll
        for (int nb = 0; nb < 4; ++nb) {
            f32x4 acc = {0.f,0.f,0.f,0.f};
            #pragma unroll
            for (int kk = 0; kk < 2; ++kk) {
                bf16x8 kf = *(const bf16x8*)(&Kl[bf][(nb*16 + l16)*64 + ((kk*32 + quad*8) ^ rswz)]);
                acc = __builtin_amdgcn_mfma_f32_16x16x32_bf16(kf, qf[kk], acc, 0, 0, 0);
            }
            s[nb] = acc;
        }
        __builtin_amdgcn_s_setprio(0);

        // ---- causal mask on the diagonal (last) tile ----
        if (t == qt) {
            #pragma unroll
            for (int nb = 0; nb < 4; ++nb)
                #pragma unroll
                for (int r = 0; r < 4; ++r)
                    if (nb*16 + quad*4 + r > relq) s[nb][r] = -1e30f;
        }

        // ---- local 16-max (tree) ----
        float a0 = fmaxf(fmaxf(s[0][0], s[0][1]), fmaxf(s[0][2], s[0][3]));
        float a1 = fmaxf(fmaxf(s[1][0], s[1][1]), fmaxf(s[1][2], s[1][3]));
        float a2 = fmaxf(fmaxf(s[2][0], s[2][1]), fmaxf(s[2][2], s[2][3]));
        float a3 = fmaxf(fmaxf(s[3][0], s[3][1]), fmaxf(s[3][2], s[3][3]));
        const float lmax = fmaxf(fmaxf(a0, a1), fmaxf(a2, a3));

        // ---- T13 defer-max: reduce+rescale only when the max grew ----
        if (!__all(lmax <= m_s + DEFER_THR)) {
            float rmax = fmaxf(lmax, __shfl_xor(lmax, 16));
            rmax = fmaxf(rmax, __shfl_xor(rmax, 32));
            const float mnew = fmaxf(m_s, rmax);
            const float cf   = __builtin_amdgcn_exp2f(m_s - mnew);
            m_s = mnew;
            l_p *= cf;
            #pragma unroll
            for (int nb = 0; nb < 4; ++nb)
                #pragma unroll
                for (int r = 0; r < 4; ++r) oacc[nb][r] *= cf;
        }

        // ---- exp2 + partial row-sum ----
        float ps[4];
        #pragma unroll
        for (int nb = 0; nb < 4; ++nb) {
            const float p0 = __builtin_amdgcn_exp2f(s[nb][0] - m_s);
            const float p1 = __builtin_amdgcn_exp2f(s[nb][1] - m_s);
            const float p2 = __builtin_amdgcn_exp2f(s[nb][2] - m_s);
            const float p3 = __builtin_amdgcn_exp2f(s[nb][3] - m_s);
            s[nb][0]=p0; s[nb][1]=p1; s[nb][2]=p2; s[nb][3]=p3;
            ps[nb] = (p0 + p1) + (p2 + p3);
        }
        l_p += (ps[0] + ps[1]) + (ps[2] + ps[3]);

        // ---- P -> Pl (uint2 pk stores), read back as B-fragment ----
        #pragma unroll
        for (int nb = 0; nb < 4; ++nb)
            *(uint2*)(&Pl[w][l16][nb*16 + quad*4]) =
                make_uint2(cvt2(s[nb][0], s[nb][1]), cvt2(s[nb][2], s[nb][3]));
        bf16x8 pfrag[2];
        #pragma unroll
        for (int kk = 0; kk < 2; ++kk)
            pfrag[kk] = *(const bf16x8*)(&Pl[w][l16][kk*32 + quad*8]);

        // ---- O^T += V^T P^T (A = Vt rows, B = P cols) ----
        __builtin_amdgcn_s_setprio(1);
        #pragma unroll
        for (int nb = 0; nb < 4; ++nb) {
            #pragma unroll
            for (int kk = 0; kk < 2; ++kk) {
                bf16x8 vf = *(const bf16x8*)(&Vl[bf][(nb*16 + l16)*64 + ((kk*32 + quad*8) ^ rswz)]);
                oacc[nb] = __builtin_amdgcn_mfma_f32_16x16x32_bf16(vf, pfrag[kk], oacc[nb], 0, 0, 0);
            }
        }
        __builtin_amdgcn_s_setprio(0);

        __syncthreads();   // drains next-tile DMA + role sync
    }

    // ---- epilogue: reduce l across quads; O^T store, float4, lane-local ----
    l_p += __shfl_xor(l_p, 16);
    l_p += __shfl_xor(l_p, 32);
    const float inv = 1.0f / l_p;
    #pragma unroll
    for (int nb = 0; nb < 4; ++nb) {
        float4 o4;
        o4.x = oacc[nb][0] * inv;
        o4.y = oacc[nb][1] * inv;
        o4.z = oacc[nb][2] * inv;
        o4.w = oacc[nb][3] * inv;
        *(float4*)(ob + nb*16 + quad*4) = o4;
    }
}

extern "C" void kernel_launch(void* const* d_in, const int* in_sizes, int n_in,
                              void* d_out, int out_size, void* d_ws, size_t ws_size,
                              hipStream_t stream) {
    const float* Q = (const float*)d_in[0];
    const float* K = (const float*)d_in[1];
    const float* V = (const float*)d_in[2];
    // d_in[3] (tril mask) computed analytically, never read.
    float* O  = (float*)d_out;
    u16*  WS = (u16*)d_ws;   // 4 MB: [2MB K tiles][2MB V tiles], bf16 swizzled

    prep_kv<<<dim3(256), dim3(256), 0, stream>>>(K, V, WS);
    gqa_fwd_kernel<<<dim3(1024), dim3(256), 0, stream>>>(Q, WS, O);
}